// Round 13
// baseline (346.620 us; speedup 1.0000x reference)
//
#include <hip/hip_runtime.h>
#include <math.h>

#define TT 1024
#define BB 8
#define EE 512
#define HH 8
#define DD 64
#define MM (TT*BB)        // 8192 rows (t*B + b)
#define NQKV (3*EE)       // 1536

typedef _Float16 f16;
typedef f16 f16x8 __attribute__((ext_vector_type(8)));
typedef f16 f16x4 __attribute__((ext_vector_type(4)));
typedef float f32x4 __attribute__((ext_vector_type(4)));

#define MFMA16 __builtin_amdgcn_mfma_f32_16x16x32_f16

// async 16B global->LDS (dest = wave-uniform base + lane*16)
typedef __attribute__((address_space(3))) void lds_t;
typedef const __attribute__((address_space(1))) void gmem_t;
__device__ inline void gld_lds16(const void* g, void* l) {
    __builtin_amdgcn_global_load_lds((gmem_t*)g, (lds_t*)l, 16, 0, 0);
}

// hardware transpose read (m156/m162): tile = addr & ~127, column = addr
// bits[6:3]; elem j = element (col + j*16) of the 4x16 f16 tile.
typedef const __attribute__((address_space(3))) f16 lds_cf16;
__device__ inline f16x4 tr16(const void* p) {
    f16x4 d;
    asm volatile("ds_read_b64_tr_b16 %0, %1" : "=v"(d) : "v"((lds_cf16*)p));
    return d;
}

// ---------------------------------------------------------------------------
// fp32 -> f16 conversion (pairs)
// ---------------------------------------------------------------------------
__global__ __launch_bounds__(256) void cvt_f16_pair(
    const float* __restrict__ sr, const float* __restrict__ si,
    f16* __restrict__ dr, f16* __restrict__ di, int n4)
{
    const int idx = blockIdx.x * 256 + threadIdx.x;
    if (idx < n4) {
        const float4 a = ((const float4*)sr)[idx];
        const float4 b = ((const float4*)si)[idx];
        f16x4 fa, fb;
        fa[0]=(f16)a.x; fa[1]=(f16)a.y; fa[2]=(f16)a.z; fa[3]=(f16)a.w;
        fb[0]=(f16)b.x; fb[1]=(f16)b.y; fb[2]=(f16)b.z; fb[3]=(f16)b.w;
        ((f16x4*)dr)[idx] = fa;
        ((f16x4*)di)[idx] = fb;
    }
}

// ---------------------------------------------------------------------------
// Complex f16 MFMA GEMM, 128x128 tile, BK=32, 4 waves (2x2), 64x64 per wave.
// ---------------------------------------------------------------------------
__global__ __launch_bounds__(256, 2) void gemm_cplx_f16(
    const f16* __restrict__ Xr, const f16* __restrict__ Xi,
    const f16* __restrict__ Wr, const f16* __restrict__ Wi,
    const float* __restrict__ biasr, const float* __restrict__ biasi,
    void* __restrict__ Yr_, void* __restrict__ Yi_,
    int N, int K, int storef16)
{
    __shared__ __attribute__((aligned(16))) f16 Asr[128][32];
    __shared__ __attribute__((aligned(16))) f16 Asi[128][32];
    __shared__ __attribute__((aligned(16))) f16 Bsr[128][32];
    __shared__ __attribute__((aligned(16))) f16 Bsi[128][32];

    const int tid  = threadIdx.x;
    const int wave = tid >> 6;
    const int lane = tid & 63;
    const int c16  = lane & 15;
    const int g    = lane >> 4;
    const int wm = wave >> 1, wn = wave & 1;
    const int m0 = blockIdx.y * 128;
    const int n0 = blockIdx.x * 128;

    const int srow = tid >> 2;
    const int sseg = tid & 3;

    f32x4 accr[4][4] = {};
    f32x4 acci[4][4] = {};

    for (int k0 = 0; k0 < K; k0 += 32) {
        __syncthreads();
        #pragma unroll
        for (int is = 0; is < 2; ++is) {
            const int row = is * 64 + srow;
            const size_t xb = (size_t)(m0 + row) * K + k0 + sseg * 8;
            const size_t wb = (size_t)(n0 + row) * K + k0 + sseg * 8;
            const int dof = is * 4096 + wave * 1024;
            gld_lds16(Xr + xb, (char*)Asr + dof);
            gld_lds16(Xi + xb, (char*)Asi + dof);
            gld_lds16(Wr + wb, (char*)Bsr + dof);
            gld_lds16(Wi + wb, (char*)Bsi + dof);
        }
        __syncthreads();

        f16x8 a_r[4], a_i[4], na_i[4];
        #pragma unroll
        for (int mi = 0; mi < 4; ++mi) {
            const int row = wm * 64 + mi * 16 + c16;
            a_r[mi] = *(const f16x8*)((const char*)Asr + row * 64 + g * 16);
            a_i[mi] = *(const f16x8*)((const char*)Asi + row * 64 + g * 16);
            na_i[mi] = -a_i[mi];
        }
        #pragma unroll
        for (int ni = 0; ni < 4; ++ni) {
            const int row = wn * 64 + ni * 16 + c16;
            const f16x8 b_r = *(const f16x8*)((const char*)Bsr + row * 64 + g * 16);
            const f16x8 b_i = *(const f16x8*)((const char*)Bsi + row * 64 + g * 16);
            #pragma unroll
            for (int mi = 0; mi < 4; ++mi) {
                accr[mi][ni] = MFMA16(a_r[mi],  b_r, accr[mi][ni], 0,0,0);
                accr[mi][ni] = MFMA16(na_i[mi], b_i, accr[mi][ni], 0,0,0);
                acci[mi][ni] = MFMA16(a_i[mi],  b_r, acci[mi][ni], 0,0,0);
                acci[mi][ni] = MFMA16(a_r[mi],  b_i, acci[mi][ni], 0,0,0);
            }
        }
    }

    float biasR[4], biasI[4];
    #pragma unroll
    for (int ni = 0; ni < 4; ++ni) {
        const int n = n0 + wn * 64 + ni * 16 + c16;
        biasR[ni] = biasr[n];
        biasI[ni] = biasi[n];
    }
    #pragma unroll
    for (int mi = 0; mi < 4; ++mi) {
        #pragma unroll
        for (int ni = 0; ni < 4; ++ni) {
            const int n = n0 + wn * 64 + ni * 16 + c16;
            #pragma unroll
            for (int rg = 0; rg < 4; ++rg) {
                const size_t m = (size_t)(m0 + wm * 64 + mi * 16 + g * 4 + rg);
                const float vr = accr[mi][ni][rg] + biasR[ni];
                const float vi = acci[mi][ni][rg] + biasI[ni];
                if (storef16) {
                    ((f16*)Yr_)[m * N + n] = (f16)vr;
                    ((f16*)Yi_)[m * N + n] = (f16)vi;
                } else {
                    ((float*)Yr_)[m * N + n] = vr;
                    ((float*)Yi_)[m * N + n] = vi;
                }
            }
        }
    }
}

// ---------------------------------------------------------------------------
// Fused complex attention v9 = round-12 structure with register-resident
// softmax (1 LDS read pass + 1 write pass), packed f16 max, pre-scaled Q.
// Grid: 512 1D blocks; b = blk&7 (XCD-pinned), qt = blk>>3.
// ---------------------------------------------------------------------------
__global__ __launch_bounds__(256, 2) void attn_mfma9(
    const f16* __restrict__ qkv_r, const f16* __restrict__ qkv_i,
    f16* __restrict__ attn_r, f16* __restrict__ attn_i,
    float* __restrict__ aw_out)
{
    // S[p][q][j] f16 at byte p*32768 + q*2048 + ((j*2) ^ ((q&7)<<4))
    __shared__ __attribute__((aligned(16))) char S[65536];
    // V ring: slot*8192 + part*4096 + wave*1024 + key*32 + dhalf*16
    __shared__ __attribute__((aligned(16))) char VR[16384];

    const int blk = blockIdx.x;
    const int b  = blk & 7;           // XCD-pinned batch
    const int qt = blk >> 3;
    const int t0 = qt * 16;
    const int tid = threadIdx.x;
    const int wave = tid >> 6, lane = tid & 63;
    const int c16 = lane & 15, g = lane >> 4;
    const int r = tid >> 4, c = tid & 15;   // softmax row / lane-in-row

    f16x8 acc8[2][8] = {};            // packed head-avg aw accumulator (64 VGPR)

    // V staging source coords (dest = wave base + lane*16)
    const int vkey = (lane >> 1) & 31;
    const int vdl  = (lane & 1) * 8;
    char* ring = VR + wave * 1024;    // per-wave private region

    f16x8 sc8;
    #pragma unroll
    for (int e = 0; e < 8; ++e) sc8[e] = (f16)0.125f;   // D^-0.5, exact in f16

    for (int h = 0; h < HH; ++h) {
        const size_t qoff = ((size_t)(t0 + c16) * BB + b) * NQKV + h * DD;
        // Q fragments pre-scaled by 0.125 (exponent shift, exact)
        const f16x8 qr0 = *(const f16x8*)(qkv_r + qoff + g * 8)      * sc8;
        const f16x8 qr1 = *(const f16x8*)(qkv_r + qoff + 32 + g * 8) * sc8;
        const f16x8 qi0 = *(const f16x8*)(qkv_i + qoff + g * 8)      * sc8;
        const f16x8 qi1 = *(const f16x8*)(qkv_i + qoff + 32 + g * 8) * sc8;
        const f16x8 nqr0 = -qr0, nqr1 = -qr1;

        // ---------------- Phase A: scores (direct global K) -----------------
        #pragma unroll 2
        for (int ch = 0; ch < 16; ++ch) {
            const int key = ch * 64 + wave * 16 + c16;
            const size_t kb = ((size_t)key * BB + b) * NQKV + EE + h * DD;
            const f16x8 kr0 = *(const f16x8*)(qkv_r + kb + g * 8);
            const f16x8 kr1 = *(const f16x8*)(qkv_r + kb + 32 + g * 8);
            const f16x8 ki0 = *(const f16x8*)(qkv_i + kb + g * 8);
            const f16x8 ki1 = *(const f16x8*)(qkv_i + kb + 32 + g * 8);
            f32x4 sr = {}, si = {};
            sr = MFMA16(qr0, kr0, sr, 0,0,0); sr = MFMA16(qr1, kr1, sr, 0,0,0);
            sr = MFMA16(qi0, ki0, sr, 0,0,0); sr = MFMA16(qi1, ki1, sr, 0,0,0);
            si = MFMA16(qi0, kr0, si, 0,0,0); si = MFMA16(qi1, kr1, si, 0,0,0);
            si = MFMA16(nqr0, ki0, si, 0,0,0); si = MFMA16(nqr1, ki1, si, 0,0,0);
            #pragma unroll
            for (int rg = 0; rg < 4; ++rg) {
                const int q = g * 4 + rg;
                const int off = q * 2048 + ((key * 2) ^ ((q & 7) << 4));
                *(f16*)(S + off)         = (f16)sr[rg];
                *(f16*)(S + 32768 + off) = (f16)si[rg];
            }
        }
        __syncthreads();

        // prefetch V ring slots 0 and 1 under the softmax
        {
            const size_t vb0 = ((size_t)vkey * BB + b) * NQKV + 2*EE + h*DD
                             + wave * 16 + vdl;
            gld_lds16(qkv_r + vb0, ring);
            gld_lds16(qkv_i + vb0, ring + 4096);
            const size_t vb1 = ((size_t)(32 + vkey) * BB + b) * NQKV + 2*EE + h*DD
                             + wave * 16 + vdl;
            gld_lds16(qkv_r + vb1, ring + 8192);
            gld_lds16(qkv_i + vb1, ring + 8192 + 4096);
        }

        // ---------------- Phase B: register-resident softmax ----------------
        #pragma unroll
        for (int p = 0; p < 2; ++p) {
            char* rowb = S + p * 32768 + r * 2048;
            const int sw = (r & 7) << 4;
            f16x8 v[8];
            #pragma unroll
            for (int i = 0; i < 8; ++i)
                v[i] = *(const f16x8*)(rowb + (((c * 8 + i * 128) * 2) ^ sw));
            // packed f16 max tree
            f16x8 m8 = v[0];
            #pragma unroll
            for (int i = 1; i < 8; ++i) {
                #pragma unroll
                for (int e = 0; e < 8; ++e)
                    m8[e] = (v[i][e] > m8[e]) ? v[i][e] : m8[e];
            }
            float m = -1e30f;
            #pragma unroll
            for (int e = 0; e < 8; ++e) m = fmaxf(m, (float)m8[e]);
            #pragma unroll
            for (int off = 8; off; off >>= 1) m = fmaxf(m, __shfl_xor(m, off, 16));
            // exp (f32) on register values
            float sum = 0.f;
            #pragma unroll
            for (int i = 0; i < 8; ++i) {
                f16x8 ev;
                #pragma unroll
                for (int e = 0; e < 8; ++e) {
                    const float x = __expf((float)v[i][e] - m);
                    ev[e] = (f16)x;
                    sum += x;
                }
                v[i] = ev;
            }
            #pragma unroll
            for (int off = 8; off; off >>= 1) sum += __shfl_xor(sum, off, 16);
            // packed normalize + accumulate + single write pass
            const f16 invh = (f16)(1.0f / sum);
            f16x8 inv8;
            #pragma unroll
            for (int e = 0; e < 8; ++e) inv8[e] = invh;
            #pragma unroll
            for (int i = 0; i < 8; ++i) {
                const f16x8 av = v[i] * inv8;
                *(f16x8*)(rowb + (((c * 8 + i * 128) * 2) ^ sw)) = av;
                acc8[p][i] += av;
            }
        }
        __syncthreads();

        // ---------------- Phase C: per-wave ring, counted vmcnt, no barriers
        f32x4 pr0 = {}, pr1 = {}, pi0 = {}, pi1 = {};
        const int arow = c16 * 2048;
        const int asw = (c16 & 7) << 4;
        #pragma unroll 2
        for (int hf = 0; hf < 32; ++hf) {
            const int slot = hf & 1;
            if (hf < 31) asm volatile("s_waitcnt vmcnt(2)" ::: "memory");
            else         asm volatile("s_waitcnt vmcnt(0)" ::: "memory");
            // tr-reads from this wave's slot (keys hf*32.., d = wave*16+c16)
            const char* vbase = ring + slot * 8192 + g * 128 + c16 * 8;
            const f16x4 vr_lo = tr16(vbase);
            const f16x4 vr_hi = tr16(vbase + 512);
            const f16x4 vi_lo = tr16(vbase + 4096);
            const f16x4 vi_hi = tr16(vbase + 4096 + 512);
            const int j0 = hf * 32 + g * 4;
            const f16x4 arlo = *(const f16x4*)(S + arow + ((j0 * 2) ^ asw));
            const f16x4 arhi = *(const f16x4*)(S + arow + (((j0 + 16) * 2) ^ asw));
            const f16x4 ailo = *(const f16x4*)(S + 32768 + arow + ((j0 * 2) ^ asw));
            const f16x4 aihi = *(const f16x4*)(S + 32768 + arow + (((j0 + 16) * 2) ^ asw));
            asm volatile("s_waitcnt lgkmcnt(0)" ::: "memory");
            __builtin_amdgcn_sched_barrier(0);
            if (hf + 2 < 32) {    // refill freed slot (reads done per lgkmcnt)
                const size_t vb = ((size_t)((hf + 2) * 32 + vkey) * BB + b) * NQKV
                                + 2*EE + h*DD + wave * 16 + vdl;
                gld_lds16(qkv_r + vb, ring + slot * 8192);
                gld_lds16(qkv_i + vb, ring + slot * 8192 + 4096);
            }
            const f16x8 vr8 = __builtin_shufflevector(vr_lo, vr_hi, 0,1,2,3,4,5,6,7);
            const f16x8 vi8 = __builtin_shufflevector(vi_lo, vi_hi, 0,1,2,3,4,5,6,7);
            const f16x8 nvi8 = -vi8;
            const f16x8 awr = __builtin_shufflevector(arlo, arhi, 0,1,2,3,4,5,6,7);
            const f16x8 awi = __builtin_shufflevector(ailo, aihi, 0,1,2,3,4,5,6,7);
            if (slot) {
                pr1 = MFMA16(awr, vr8,  pr1, 0,0,0);
                pr1 = MFMA16(awi, vi8,  pr1, 0,0,0);
                pi1 = MFMA16(awi, vr8,  pi1, 0,0,0);
                pi1 = MFMA16(awr, nvi8, pi1, 0,0,0);
            } else {
                pr0 = MFMA16(awr, vr8,  pr0, 0,0,0);
                pr0 = MFMA16(awi, vi8,  pr0, 0,0,0);
                pi0 = MFMA16(awi, vr8,  pi0, 0,0,0);
                pi0 = MFMA16(awr, nvi8, pi0, 0,0,0);
            }
        }
        const f32x4 pr = pr0 + pr1, pi = pi0 + pi1;
        __syncthreads();   // S consumed; safe for next head's Phase A writes

        #pragma unroll
        for (int rg = 0; rg < 4; ++rg) {
            const int q = g * 4 + rg;
            const int d = wave * 16 + c16;
            const size_t ob = ((size_t)(t0 + q) * BB + b) * EE + h * DD + d;
            attn_r[ob] = (f16)pr[rg];
            attn_i[ob] = (f16)pi[rg];
        }
    }

    // final head-averaged aw write (exclusive rows)
    #pragma unroll
    for (int p = 0; p < 2; ++p) {
        float* dst = aw_out + (size_t)p * BB * TT * TT + ((size_t)b * TT + t0 + r) * TT;
        #pragma unroll
        for (int i = 0; i < 8; ++i) {
            const int j = c * 8 + i * 128;
            float4 v0, v1;
            v0.x = (float)acc8[p][i][0] * 0.125f; v0.y = (float)acc8[p][i][1] * 0.125f;
            v0.z = (float)acc8[p][i][2] * 0.125f; v0.w = (float)acc8[p][i][3] * 0.125f;
            v1.x = (float)acc8[p][i][4] * 0.125f; v1.y = (float)acc8[p][i][5] * 0.125f;
            v1.z = (float)acc8[p][i][6] * 0.125f; v1.w = (float)acc8[p][i][7] * 0.125f;
            *(float4*)(dst + j) = v0;
            *(float4*)(dst + j + 4) = v1;
        }
    }
}

// ---------------------------------------------------------------------------
extern "C" void kernel_launch(void* const* d_in, const int* in_sizes, int n_in,
                              void* d_out, int out_size, void* d_ws, size_t ws_size,
                              hipStream_t stream)
{
    const float* query_r = (const float*)d_in[0];
    const float* query_i = (const float*)d_in[1];
    const float* W_qkv_r = (const float*)d_in[2];
    const float* W_qkv_i = (const float*)d_in[3];
    const float* b_qkv_r = (const float*)d_in[4];
    const float* b_qkv_i = (const float*)d_in[5];
    const float* W_out_r = (const float*)d_in[6];
    const float* W_out_i = (const float*)d_in[7];
    const float* b_out_r = (const float*)d_in[8];
    const float* b_out_i = (const float*)d_in[9];

    char* w = (char*)d_ws;
    f16* q16_r = (f16*)(w);
    f16* q16_i = (f16*)(w + 8388608);
    f16* Wq_r  = (f16*)(w + 16777216);
    f16* Wq_i  = (f16*)(w + 18350080);
    f16* Wo_r  = (f16*)(w + 19922944);
    f16* Wo_i  = (f16*)(w + 20447232);
    f16* qkv_r = (f16*)(w + 20971520);
    f16* qkv_i = (f16*)(w + 46137344);
    f16* at_r  = (f16*)(w + 71303168);
    f16* at_i  = (f16*)(w + 79691776);

    float* out   = (float*)d_out;
    float* out_r = out;
    float* out_i = out + (size_t)MM * EE;
    float* aw    = out + 2 * (size_t)MM * EE;   // [2][B][T][T]

    // fp32 -> f16 conversions
    {
        const int n4q = MM * EE / 4;
        cvt_f16_pair<<<dim3((n4q + 255) / 256), dim3(256), 0, stream>>>(
            query_r, query_i, q16_r, q16_i, n4q);
        const int n4wq = NQKV * EE / 4;
        cvt_f16_pair<<<dim3((n4wq + 255) / 256), dim3(256), 0, stream>>>(
            W_qkv_r, W_qkv_i, Wq_r, Wq_i, n4wq);
        const int n4wo = EE * EE / 4;
        cvt_f16_pair<<<dim3((n4wo + 255) / 256), dim3(256), 0, stream>>>(
            W_out_r, W_out_i, Wo_r, Wo_i, n4wo);
    }
    // QKV projection (complex f16 MFMA), stores f16
    gemm_cplx_f16<<<dim3(NQKV / 128, MM / 128), dim3(256), 0, stream>>>(
        q16_r, q16_i, Wq_r, Wq_i, b_qkv_r, b_qkv_i,
        (void*)qkv_r, (void*)qkv_i, NQKV, EE, 1);
    // fused attention (XCD-swizzled 1D grid)
    attn_mfma9<<<dim3(TT / 16 * BB), dim3(256), 0, stream>>>(
        qkv_r, qkv_i, at_r, at_i, aw);
    // output projection (complex f16 MFMA), stores f32 to d_out
    gemm_cplx_f16<<<dim3(EE / 128, MM / 128), dim3(256), 0, stream>>>(
        at_r, at_i, Wo_r, Wo_i, b_out_r, b_out_i,
        (void*)out_r, (void*)out_i, EE, EE, 0);
}

// Round 14
// 343.129 us; speedup vs baseline: 1.0102x; 1.0102x over previous
//
#include <hip/hip_runtime.h>
#include <math.h>

#define TT 1024
#define BB 8
#define EE 512
#define HH 8
#define DD 64
#define MM (TT*BB)        // 8192 rows (t*B + b)
#define NQKV (3*EE)       // 1536

typedef _Float16 f16;
typedef f16 f16x8 __attribute__((ext_vector_type(8)));
typedef f16 f16x4 __attribute__((ext_vector_type(4)));
typedef float f32x4 __attribute__((ext_vector_type(4)));

#define MFMA16 __builtin_amdgcn_mfma_f32_16x16x32_f16

// async 16B global->LDS (dest = wave-uniform base + lane*16)
typedef __attribute__((address_space(3))) void lds_t;
typedef const __attribute__((address_space(1))) void gmem_t;
__device__ inline void gld_lds16(const void* g, void* l) {
    __builtin_amdgcn_global_load_lds((gmem_t*)g, (lds_t*)l, 16, 0, 0);
}

// hardware transpose read (m156/m162): tile = addr & ~127, column = addr
// bits[6:3]; elem j = row j of the 4x16 f16 tile at that column.
typedef const __attribute__((address_space(3))) f16 lds_cf16;
__device__ inline f16x4 tr16(const void* p) {
    f16x4 d;
    asm volatile("ds_read_b64_tr_b16 %0, %1" : "=v"(d) : "v"((lds_cf16*)p));
    return d;
}

// ---------------------------------------------------------------------------
// fp32 -> f16 conversion (pairs)
// ---------------------------------------------------------------------------
__global__ __launch_bounds__(256) void cvt_f16_pair(
    const float* __restrict__ sr, const float* __restrict__ si,
    f16* __restrict__ dr, f16* __restrict__ di, int n4)
{
    const int idx = blockIdx.x * 256 + threadIdx.x;
    if (idx < n4) {
        const float4 a = ((const float4*)sr)[idx];
        const float4 b = ((const float4*)si)[idx];
        f16x4 fa, fb;
        fa[0]=(f16)a.x; fa[1]=(f16)a.y; fa[2]=(f16)a.z; fa[3]=(f16)a.w;
        fb[0]=(f16)b.x; fb[1]=(f16)b.y; fb[2]=(f16)b.z; fb[3]=(f16)b.w;
        ((f16x4*)dr)[idx] = fa;
        ((f16x4*)di)[idx] = fb;
    }
}

// ---------------------------------------------------------------------------
// Complex f16 MFMA GEMM, 128x128 tile, BK=32, 4 waves (2x2), 64x64 per wave.
// ---------------------------------------------------------------------------
__global__ __launch_bounds__(256, 2) void gemm_cplx_f16(
    const f16* __restrict__ Xr, const f16* __restrict__ Xi,
    const f16* __restrict__ Wr, const f16* __restrict__ Wi,
    const float* __restrict__ biasr, const float* __restrict__ biasi,
    void* __restrict__ Yr_, void* __restrict__ Yi_,
    int N, int K, int storef16)
{
    __shared__ __attribute__((aligned(16))) f16 Asr[128][32];
    __shared__ __attribute__((aligned(16))) f16 Asi[128][32];
    __shared__ __attribute__((aligned(16))) f16 Bsr[128][32];
    __shared__ __attribute__((aligned(16))) f16 Bsi[128][32];

    const int tid  = threadIdx.x;
    const int wave = tid >> 6;
    const int lane = tid & 63;
    const int c16  = lane & 15;
    const int g    = lane >> 4;
    const int wm = wave >> 1, wn = wave & 1;
    const int m0 = blockIdx.y * 128;
    const int n0 = blockIdx.x * 128;

    const int srow = tid >> 2;
    const int sseg = tid & 3;

    f32x4 accr[4][4] = {};
    f32x4 acci[4][4] = {};

    for (int k0 = 0; k0 < K; k0 += 32) {
        __syncthreads();
        #pragma unroll
        for (int is = 0; is < 2; ++is) {
            const int row = is * 64 + srow;
            const size_t xb = (size_t)(m0 + row) * K + k0 + sseg * 8;
            const size_t wb = (size_t)(n0 + row) * K + k0 + sseg * 8;
            const int dof = is * 4096 + wave * 1024;
            gld_lds16(Xr + xb, (char*)Asr + dof);
            gld_lds16(Xi + xb, (char*)Asi + dof);
            gld_lds16(Wr + wb, (char*)Bsr + dof);
            gld_lds16(Wi + wb, (char*)Bsi + dof);
        }
        __syncthreads();

        f16x8 a_r[4], a_i[4], na_i[4];
        #pragma unroll
        for (int mi = 0; mi < 4; ++mi) {
            const int row = wm * 64 + mi * 16 + c16;
            a_r[mi] = *(const f16x8*)((const char*)Asr + row * 64 + g * 16);
            a_i[mi] = *(const f16x8*)((const char*)Asi + row * 64 + g * 16);
            na_i[mi] = -a_i[mi];
        }
        #pragma unroll
        for (int ni = 0; ni < 4; ++ni) {
            const int row = wn * 64 + ni * 16 + c16;
            const f16x8 b_r = *(const f16x8*)((const char*)Bsr + row * 64 + g * 16);
            const f16x8 b_i = *(const f16x8*)((const char*)Bsi + row * 64 + g * 16);
            #pragma unroll
            for (int mi = 0; mi < 4; ++mi) {
                accr[mi][ni] = MFMA16(a_r[mi],  b_r, accr[mi][ni], 0,0,0);
                accr[mi][ni] = MFMA16(na_i[mi], b_i, accr[mi][ni], 0,0,0);
                acci[mi][ni] = MFMA16(a_i[mi],  b_r, acci[mi][ni], 0,0,0);
                acci[mi][ni] = MFMA16(a_r[mi],  b_i, acci[mi][ni], 0,0,0);
            }
        }
    }

    float biasR[4], biasI[4];
    #pragma unroll
    for (int ni = 0; ni < 4; ++ni) {
        const int n = n0 + wn * 64 + ni * 16 + c16;
        biasR[ni] = biasr[n];
        biasI[ni] = biasi[n];
    }
    #pragma unroll
    for (int mi = 0; mi < 4; ++mi) {
        #pragma unroll
        for (int ni = 0; ni < 4; ++ni) {
            const int n = n0 + wn * 64 + ni * 16 + c16;
            #pragma unroll
            for (int rg = 0; rg < 4; ++rg) {
                const size_t m = (size_t)(m0 + wm * 64 + mi * 16 + g * 4 + rg);
                const float vr = accr[mi][ni][rg] + biasR[ni];
                const float vi = acci[mi][ni][rg] + biasI[ni];
                if (storef16) {
                    ((f16*)Yr_)[m * N + n] = (f16)vr;
                    ((f16*)Yi_)[m * N + n] = (f16)vi;
                } else {
                    ((float*)Yr_)[m * N + n] = vr;
                    ((float*)Yi_)[m * N + n] = vi;
                }
            }
        }
    }
}

// ---------------------------------------------------------------------------
// Fused complex attention v10 = round-13 structure with:
//  - QK^T operands swapped: D[key_local][q] -> S-store = 1 ds_write_b64/part
//  - identity k-map PV: aw reads = b128, tr16 tiles at g*256/+128
// Grid: 512 1D blocks; b = blk&7 (XCD-pinned), qt = blk>>3.
// ---------------------------------------------------------------------------
__global__ __launch_bounds__(256, 2) void attn_mfma10(
    const f16* __restrict__ qkv_r, const f16* __restrict__ qkv_i,
    f16* __restrict__ attn_r, f16* __restrict__ attn_i,
    float* __restrict__ aw_out)
{
    // S[p][q][j] f16 at byte p*32768 + q*2048 + ((j*2) ^ ((q&7)<<4))
    __shared__ __attribute__((aligned(16))) char S[65536];
    // V ring: slot*8192 + part*4096 + wave*1024 + key*32 + dl*2 (key<32, dl<16)
    __shared__ __attribute__((aligned(16))) char VR[16384];

    const int blk = blockIdx.x;
    const int b  = blk & 7;           // XCD-pinned batch
    const int qt = blk >> 3;
    const int t0 = qt * 16;
    const int tid = threadIdx.x;
    const int wave = tid >> 6, lane = tid & 63;
    const int c16 = lane & 15, g = lane >> 4;
    const int r = tid >> 4, c = tid & 15;   // softmax row / lane-in-row

    f16x8 acc8[2][8] = {};            // packed head-avg aw accumulator (64 VGPR)

    // V staging source coords (dest = wave base + lane*16)
    const int vkey = (lane >> 1) & 31;
    const int vdl  = (lane & 1) * 8;
    char* ring = VR + wave * 1024;    // per-wave private region

    f16x8 sc8;
    #pragma unroll
    for (int e = 0; e < 8; ++e) sc8[e] = (f16)0.125f;   // D^-0.5, exact in f16

    for (int h = 0; h < HH; ++h) {
        const size_t qoff = ((size_t)(t0 + c16) * BB + b) * NQKV + h * DD;
        // Q fragments pre-scaled by 0.125 (exponent shift, exact)
        const f16x8 qr0 = *(const f16x8*)(qkv_r + qoff + g * 8)      * sc8;
        const f16x8 qr1 = *(const f16x8*)(qkv_r + qoff + 32 + g * 8) * sc8;
        const f16x8 qi0 = *(const f16x8*)(qkv_i + qoff + g * 8)      * sc8;
        const f16x8 qi1 = *(const f16x8*)(qkv_i + qoff + 32 + g * 8) * sc8;
        const f16x8 nqr0 = -qr0, nqr1 = -qr1;

        // ------ Phase A: scores, swapped operands: D[key_local][q=c16] ------
        #pragma unroll 2
        for (int ch = 0; ch < 16; ++ch) {
            const int key = ch * 64 + wave * 16 + c16;      // A-operand row
            const size_t kb = ((size_t)key * BB + b) * NQKV + EE + h * DD;
            const f16x8 kr0 = *(const f16x8*)(qkv_r + kb + g * 8);
            const f16x8 kr1 = *(const f16x8*)(qkv_r + kb + 32 + g * 8);
            const f16x8 ki0 = *(const f16x8*)(qkv_i + kb + g * 8);
            const f16x8 ki1 = *(const f16x8*)(qkv_i + kb + 32 + g * 8);
            f32x4 sr = {}, si = {};
            sr = MFMA16(kr0, qr0, sr, 0,0,0); sr = MFMA16(kr1, qr1, sr, 0,0,0);
            sr = MFMA16(ki0, qi0, sr, 0,0,0); sr = MFMA16(ki1, qi1, sr, 0,0,0);
            si = MFMA16(kr0, qi0, si, 0,0,0); si = MFMA16(kr1, qi1, si, 0,0,0);
            si = MFMA16(ki0, nqr0, si, 0,0,0); si = MFMA16(ki1, nqr1, si, 0,0,0);
            // lane holds S[q=c16][key0 + rg], rg=0..3 -> one b64 store per part
            const int key0 = ch * 64 + wave * 16 + g * 4;
            f16x4 s4r, s4i;
            #pragma unroll
            for (int e = 0; e < 4; ++e) { s4r[e] = (f16)sr[e]; s4i[e] = (f16)si[e]; }
            const int off = c16 * 2048 + ((key0 * 2) ^ ((c16 & 7) << 4));
            *(f16x4*)(S + off)         = s4r;
            *(f16x4*)(S + 32768 + off) = s4i;
        }
        __syncthreads();

        // prefetch V ring slots 0 and 1 under the softmax
        {
            const size_t vb0 = ((size_t)vkey * BB + b) * NQKV + 2*EE + h*DD
                             + wave * 16 + vdl;
            gld_lds16(qkv_r + vb0, ring);
            gld_lds16(qkv_i + vb0, ring + 4096);
            const size_t vb1 = ((size_t)(32 + vkey) * BB + b) * NQKV + 2*EE + h*DD
                             + wave * 16 + vdl;
            gld_lds16(qkv_r + vb1, ring + 8192);
            gld_lds16(qkv_i + vb1, ring + 8192 + 4096);
        }

        // ---------------- Phase B: register-resident softmax ----------------
        #pragma unroll
        for (int p = 0; p < 2; ++p) {
            char* rowb = S + p * 32768 + r * 2048;
            const int sw = (r & 7) << 4;
            f16x8 v[8];
            #pragma unroll
            for (int i = 0; i < 8; ++i)
                v[i] = *(const f16x8*)(rowb + (((c * 8 + i * 128) * 2) ^ sw));
            f16x8 m8 = v[0];
            #pragma unroll
            for (int i = 1; i < 8; ++i) {
                #pragma unroll
                for (int e = 0; e < 8; ++e)
                    m8[e] = (v[i][e] > m8[e]) ? v[i][e] : m8[e];
            }
            float m = -1e30f;
            #pragma unroll
            for (int e = 0; e < 8; ++e) m = fmaxf(m, (float)m8[e]);
            #pragma unroll
            for (int off = 8; off; off >>= 1) m = fmaxf(m, __shfl_xor(m, off, 16));
            float sum = 0.f;
            #pragma unroll
            for (int i = 0; i < 8; ++i) {
                f16x8 ev;
                #pragma unroll
                for (int e = 0; e < 8; ++e) {
                    const float x = __expf((float)v[i][e] - m);
                    ev[e] = (f16)x;
                    sum += x;
                }
                v[i] = ev;
            }
            #pragma unroll
            for (int off = 8; off; off >>= 1) sum += __shfl_xor(sum, off, 16);
            const f16 invh = (f16)(1.0f / sum);
            f16x8 inv8;
            #pragma unroll
            for (int e = 0; e < 8; ++e) inv8[e] = invh;
            #pragma unroll
            for (int i = 0; i < 8; ++i) {
                const f16x8 av = v[i] * inv8;
                *(f16x8*)(rowb + (((c * 8 + i * 128) * 2) ^ sw)) = av;
                acc8[p][i] += av;
            }
        }
        __syncthreads();

        // -------- Phase C: identity k-map, b128 aw reads, counted vmcnt -----
        f32x4 pr0 = {}, pr1 = {}, pi0 = {}, pi1 = {};
        const int arow = c16 * 2048;
        const int asw = (c16 & 7) << 4;
        #pragma unroll 2
        for (int hf = 0; hf < 32; ++hf) {
            const int slot = hf & 1;
            if (hf < 31) asm volatile("s_waitcnt vmcnt(2)" ::: "memory");
            else         asm volatile("s_waitcnt vmcnt(0)" ::: "memory");
            // tr-reads: tiles 2g, 2g+1 -> keys 8g..8g+7 (identity k-map)
            const char* vbase = ring + slot * 8192 + g * 256 + c16 * 8;
            const f16x4 vr_lo = tr16(vbase);
            const f16x4 vr_hi = tr16(vbase + 128);
            const f16x4 vi_lo = tr16(vbase + 4096);
            const f16x4 vi_hi = tr16(vbase + 4096 + 128);
            const int j0 = hf * 32 + g * 8;
            const f16x8 awr = *(const f16x8*)(S + arow + ((j0 * 2) ^ asw));
            const f16x8 awi = *(const f16x8*)(S + 32768 + arow + ((j0 * 2) ^ asw));
            asm volatile("s_waitcnt lgkmcnt(0)" ::: "memory");
            __builtin_amdgcn_sched_barrier(0);
            if (hf + 2 < 32) {    // refill freed slot (reads done per lgkmcnt)
                const size_t vb = ((size_t)((hf + 2) * 32 + vkey) * BB + b) * NQKV
                                + 2*EE + h*DD + wave * 16 + vdl;
                gld_lds16(qkv_r + vb, ring + slot * 8192);
                gld_lds16(qkv_i + vb, ring + slot * 8192 + 4096);
            }
            const f16x8 vr8 = __builtin_shufflevector(vr_lo, vr_hi, 0,1,2,3,4,5,6,7);
            const f16x8 vi8 = __builtin_shufflevector(vi_lo, vi_hi, 0,1,2,3,4,5,6,7);
            const f16x8 nvi8 = -vi8;
            if (slot) {
                pr1 = MFMA16(awr, vr8,  pr1, 0,0,0);
                pr1 = MFMA16(awi, vi8,  pr1, 0,0,0);
                pi1 = MFMA16(awi, vr8,  pi1, 0,0,0);
                pi1 = MFMA16(awr, nvi8, pi1, 0,0,0);
            } else {
                pr0 = MFMA16(awr, vr8,  pr0, 0,0,0);
                pr0 = MFMA16(awi, vi8,  pr0, 0,0,0);
                pi0 = MFMA16(awi, vr8,  pi0, 0,0,0);
                pi0 = MFMA16(awr, nvi8, pi0, 0,0,0);
            }
        }
        const f32x4 pr = pr0 + pr1, pi = pi0 + pi1;
        __syncthreads();   // S consumed; safe for next head's Phase A writes

        #pragma unroll
        for (int rg = 0; rg < 4; ++rg) {
            const int q = g * 4 + rg;
            const int d = wave * 16 + c16;
            const size_t ob = ((size_t)(t0 + q) * BB + b) * EE + h * DD + d;
            attn_r[ob] = (f16)pr[rg];
            attn_i[ob] = (f16)pi[rg];
        }
    }

    // final head-averaged aw write (exclusive rows)
    #pragma unroll
    for (int p = 0; p < 2; ++p) {
        float* dst = aw_out + (size_t)p * BB * TT * TT + ((size_t)b * TT + t0 + r) * TT;
        #pragma unroll
        for (int i = 0; i < 8; ++i) {
            const int j = c * 8 + i * 128;
            float4 v0, v1;
            v0.x = (float)acc8[p][i][0] * 0.125f; v0.y = (float)acc8[p][i][1] * 0.125f;
            v0.z = (float)acc8[p][i][2] * 0.125f; v0.w = (float)acc8[p][i][3] * 0.125f;
            v1.x = (float)acc8[p][i][4] * 0.125f; v1.y = (float)acc8[p][i][5] * 0.125f;
            v1.z = (float)acc8[p][i][6] * 0.125f; v1.w = (float)acc8[p][i][7] * 0.125f;
            *(float4*)(dst + j) = v0;
            *(float4*)(dst + j + 4) = v1;
        }
    }
}

// ---------------------------------------------------------------------------
extern "C" void kernel_launch(void* const* d_in, const int* in_sizes, int n_in,
                              void* d_out, int out_size, void* d_ws, size_t ws_size,
                              hipStream_t stream)
{
    const float* query_r = (const float*)d_in[0];
    const float* query_i = (const float*)d_in[1];
    const float* W_qkv_r = (const float*)d_in[2];
    const float* W_qkv_i = (const float*)d_in[3];
    const float* b_qkv_r = (const float*)d_in[4];
    const float* b_qkv_i = (const float*)d_in[5];
    const float* W_out_r = (const float*)d_in[6];
    const float* W_out_i = (const float*)d_in[7];
    const float* b_out_r = (const float*)d_in[8];
    const float* b_out_i = (const float*)d_in[9];

    char* w = (char*)d_ws;
    f16* q16_r = (f16*)(w);
    f16* q16_i = (f16*)(w + 8388608);
    f16* Wq_r  = (f16*)(w + 16777216);
    f16* Wq_i  = (f16*)(w + 18350080);
    f16* Wo_r  = (f16*)(w + 19922944);
    f16* Wo_i  = (f16*)(w + 20447232);
    f16* qkv_r = (f16*)(w + 20971520);
    f16* qkv_i = (f16*)(w + 46137344);
    f16* at_r  = (f16*)(w + 71303168);
    f16* at_i  = (f16*)(w + 79691776);

    float* out   = (float*)d_out;
    float* out_r = out;
    float* out_i = out + (size_t)MM * EE;
    float* aw    = out + 2 * (size_t)MM * EE;   // [2][B][T][T]

    // fp32 -> f16 conversions
    {
        const int n4q = MM * EE / 4;
        cvt_f16_pair<<<dim3((n4q + 255) / 256), dim3(256), 0, stream>>>(
            query_r, query_i, q16_r, q16_i, n4q);
        const int n4wq = NQKV * EE / 4;
        cvt_f16_pair<<<dim3((n4wq + 255) / 256), dim3(256), 0, stream>>>(
            W_qkv_r, W_qkv_i, Wq_r, Wq_i, n4wq);
        const int n4wo = EE * EE / 4;
        cvt_f16_pair<<<dim3((n4wo + 255) / 256), dim3(256), 0, stream>>>(
            W_out_r, W_out_i, Wo_r, Wo_i, n4wo);
    }
    // QKV projection (complex f16 MFMA), stores f16
    gemm_cplx_f16<<<dim3(NQKV / 128, MM / 128), dim3(256), 0, stream>>>(
        q16_r, q16_i, Wq_r, Wq_i, b_qkv_r, b_qkv_i,
        (void*)qkv_r, (void*)qkv_i, NQKV, EE, 1);
    // fused attention (XCD-swizzled 1D grid)
    attn_mfma10<<<dim3(TT / 16 * BB), dim3(256), 0, stream>>>(
        qkv_r, qkv_i, at_r, at_i, aw);
    // output projection (complex f16 MFMA), stores f32 to d_out
    gemm_cplx_f16<<<dim3(EE / 128, MM / 128), dim3(256), 0, stream>>>(
        at_r, at_i, Wo_r, Wo_i, b_out_r, b_out_i,
        (void*)out_r, (void*)out_i, EE, EE, 0);
}